// Round 2
// baseline (97.468 us; speedup 1.0000x reference)
//
#include <hip/hip_runtime.h>
#include <math.h>

#define DIM 2048
#define NB 32
#define NK 256
#define KPB 2   // k-values per block in softmax kernel

// ---------------- Kernel A: Bsum[b,i] = sum_j |s[b,i] - s[b,j]| ----------------
// grid (8, 32): x = i-chunk of 256, y = batch. 256 threads, one i per thread.
// Whole 2048-float row staged in LDS (8 KiB); inner loop reads float4 broadcasts
// (wave-uniform LDS address -> conflict-free). No atomics, no memset needed.
__global__ __launch_bounds__(256) void bsum_kernel(const float* __restrict__ scores,
                                                   float* __restrict__ bsum) {
    __shared__ float4 srow[DIM / 4];  // 8 KiB
    const int b = blockIdx.y;
    const int t = threadIdx.x;
    const float* row = scores + b * DIM;

    srow[t]       = ((const float4*)row)[t];
    srow[t + 256] = ((const float4*)row)[t + 256];
    __syncthreads();

    const int i = blockIdx.x * 256 + t;
    const float xi = ((const float*)srow)[i];  // lane-consecutive -> 2-way bank alias (free)

    float a0 = 0.f, a1 = 0.f, a2 = 0.f, a3 = 0.f;
    #pragma unroll 4
    for (int jj = 0; jj < DIM / 4; ++jj) {
        const float4 xj = srow[jj];
        a0 += fabsf(xi - xj.x);
        a1 += fabsf(xi - xj.y);
        a2 += fabsf(xi - xj.z);
        a3 += fabsf(xi - xj.w);
    }
    bsum[b * DIM + i] = (a0 + a1) + (a2 + a3);
}

// ---------------- Kernel B: row softmax over i for each (b,k) ----------------
// grid (NK/KPB, NB), 64 threads = ONE wave per block: no barriers, pure shuffle
// reductions. Each thread holds 32 elements (8 float4, lane-contiguous chunks).
// KPB k-values share the loaded scores/Bsum registers.
__global__ __launch_bounds__(64) void softmax_kernel(const float* __restrict__ scores,
                                                     const float* __restrict__ bsum,
                                                     float* __restrict__ out) {
    const int b  = blockIdx.y;
    const int k0 = blockIdx.x * KPB;
    const int t  = threadIdx.x;

    const float4* s4  = (const float4*)(scores + b * DIM);
    const float4* bs4 = (const float4*)(bsum   + b * DIM);

    float4 sv[8], bv[8];
    #pragma unroll
    for (int q = 0; q < 8; ++q) {
        sv[q] = s4[t + 64 * q];   // each load: 64 lanes x 16 B contiguous
        bv[q] = bs4[t + 64 * q];
    }

    #pragma unroll
    for (int kk = 0; kk < KPB; ++kk) {
        const int k = k0 + kk;
        const float scale = (float)(DIM - 1 - 2 * k);  // 2047 - 2k

        float e[32];
        #pragma unroll
        for (int q = 0; q < 8; ++q) {
            e[4 * q + 0] = fmaf(sv[q].x, scale, -bv[q].x);
            e[4 * q + 1] = fmaf(sv[q].y, scale, -bv[q].y);
            e[4 * q + 2] = fmaf(sv[q].z, scale, -bv[q].z);
            e[4 * q + 3] = fmaf(sv[q].w, scale, -bv[q].w);
        }

        // local max tree (4 parallel chains), then 6-step wave butterfly
        float m0 = e[0], m1 = e[1], m2 = e[2], m3 = e[3];
        #pragma unroll
        for (int j = 4; j < 32; j += 4) {
            m0 = fmaxf(m0, e[j + 0]);
            m1 = fmaxf(m1, e[j + 1]);
            m2 = fmaxf(m2, e[j + 2]);
            m3 = fmaxf(m3, e[j + 3]);
        }
        float m = fmaxf(fmaxf(m0, m1), fmaxf(m2, m3));
        #pragma unroll
        for (int off = 32; off > 0; off >>= 1) m = fmaxf(m, __shfl_xor(m, off, 64));

        // exp + local sum (4 chains), then wave butterfly
        float s0 = 0.f, s1 = 0.f, s2 = 0.f, s3 = 0.f;
        #pragma unroll
        for (int j = 0; j < 32; j += 4) {
            e[j + 0] = __expf(e[j + 0] - m); s0 += e[j + 0];
            e[j + 1] = __expf(e[j + 1] - m); s1 += e[j + 1];
            e[j + 2] = __expf(e[j + 2] - m); s2 += e[j + 2];
            e[j + 3] = __expf(e[j + 3] - m); s3 += e[j + 3];
        }
        float s = (s0 + s1) + (s2 + s3);
        #pragma unroll
        for (int off = 32; off > 0; off >>= 1) s += __shfl_xor(s, off, 64);

        const float inv = 1.f / s;
        float4* o4 = (float4*)(out + ((size_t)(b * NK + k)) * DIM);
        #pragma unroll
        for (int q = 0; q < 8; ++q) {
            float4 o;
            o.x = e[4 * q + 0] * inv;
            o.y = e[4 * q + 1] * inv;
            o.z = e[4 * q + 2] * inv;
            o.w = e[4 * q + 3] * inv;
            o4[t + 64 * q] = o;   // contiguous 4 KiB per store instruction
        }
    }
}

extern "C" void kernel_launch(void* const* d_in, const int* in_sizes, int n_in,
                              void* d_out, int out_size, void* d_ws, size_t ws_size,
                              hipStream_t stream) {
    const float* scores = (const float*)d_in[0];
    float* out  = (float*)d_out;
    float* bsum = (float*)d_ws;  // NB*DIM floats = 256 KiB

    bsum_kernel<<<dim3(8, NB), 256, 0, stream>>>(scores, bsum);
    softmax_kernel<<<dim3(NK / KPB, NB), 64, 0, stream>>>(scores, bsum, out);
}